// Round 9
// baseline (3244.450 us; speedup 1.0000x reference)
//
#include <hip/hip_runtime.h>

#define T_SEQ   1024
#define INDIM   6
#define HDIM    64
#define NPRED   10
#define CHNK    32
#define S0      104      // LDS row stride (elements) for A-operand buffers
#define NROWS   16       // batch rows per workgroup (grid 256 = 1 block/CU)
#define GSTR    20       // G-buffer stride in floats per gate-col (80 B, 16B-aligned)

typedef __bf16         bf16x8 __attribute__((ext_vector_type(8)));
typedef float          f32x4  __attribute__((ext_vector_type(4)));
typedef unsigned short us4    __attribute__((ext_vector_type(4)));

#define MFMA16(a, b, c) __builtin_amdgcn_mfma_f32_16x16x32_bf16((a), (b), (c), 0, 0, 0)

static __device__ __forceinline__ float bf2f(unsigned short b) {
  union { unsigned int u; float f; } v; v.u = ((unsigned int)b) << 16; return v.f;
}
static __device__ __forceinline__ unsigned short f2bf(float f) {
  union { float f; unsigned int u; } v; v.f = f;
  unsigned int r = v.u + 0x7FFFu + ((v.u >> 16) & 1u);
  return (unsigned short)(r >> 16);
}
static __device__ __forceinline__ float sigf(float x) {
  return __builtin_amdgcn_rcpf(1.0f + __builtin_amdgcn_exp2f(x * -1.442695040888963f));
}
static __device__ __forceinline__ float tanh_f(float x) {
  return 2.0f * __builtin_amdgcn_rcpf(1.0f + __builtin_amdgcn_exp2f(x * -2.885390081777927f)) - 1.0f;
}

// Role-split 2-layer LSTM, 1024 threads, 1 block/CU (grid 256), NROWS=16,
// zero phantom rows. Roles by wave: 0-3 L0-MFMA -> G0(f32), 4-7 L1-MFMA
// (lag 1 step) -> G1, 8-11 L0-activation (c0 in regs), 12-15 L1-activation.
// 2 barriers/encoder step. Dual-dtype via verified bit-pattern sniff.
template <bool F32>
__global__ __launch_bounds__(1024, 1)
void lstm2_split(const void* __restrict__ xv,
                 const void* __restrict__ Wih0v,
                 const void* __restrict__ Whh0v,
                 const void* __restrict__ bih0v,
                 const void* __restrict__ bhh0v,
                 const void* __restrict__ Wih1v,
                 const void* __restrict__ Whh1v,
                 const void* __restrict__ bih1v,
                 const void* __restrict__ bhh1v,
                 const void* __restrict__ fcwv,
                 const void* __restrict__ fcbv,
                 void* __restrict__ outv)
{
  // ---- dtype sniff (uniform) ----
  {
    const unsigned short* w0u = (const unsigned short*)Wih0v;
    int votes = 0;
#pragma unroll
    for (int i = 0; i < 16; ++i) {
      const unsigned e = (w0u[2 * i] >> 7) & 0xFF;
      votes += (e >= 0x80 || e <= 0x40) ? 1 : 0;
    }
    if ((votes >= 4) != F32) return;
  }

  __shared__ __align__(16) unsigned short A0[2][NROWS * S0];   // h0 ++ x ++ pad
  __shared__ __align__(16) unsigned short A1[2][NROWS * S0];   // h1
  __shared__ __align__(16) float G0[4 * HDIM * GSTR];          // L0 raw gates f32
  __shared__ __align__(16) float G1[4 * HDIM * GSTR];          // L1 raw gates f32
  __shared__ __align__(16) unsigned short XB[NROWS * CHNK * INDIM];
  __shared__ __align__(16) unsigned short FCW[INDIM * HDIM];
  __shared__ float FCB[INDIM];

  const int tid  = threadIdx.x;
  const int lane = tid & 63;
  const int wave = tid >> 6;
  const int role = wave >> 2;   // 0 A-MFMA, 1 B-MFMA, 2 act-L0, 3 act-L1
  const int wv   = wave & 3;    // role-local wave id
  const int q    = lane >> 4;
  const int n    = lane & 15;
  const int u    = 16 * wv + n; // MFMA roles: owned unit col
  const int rbase = blockIdx.x * NROWS;

  // ---- zero state buffers ----
  {
    unsigned short* p0 = &A0[0][0];
    unsigned short* p1 = &A1[0][0];
    for (int i = tid; i < 2 * NROWS * S0; i += 1024) { p0[i] = 0; p1[i] = 0; }
  }
  for (int i = tid; i < INDIM * HDIM; i += 1024) {
    if constexpr (F32) FCW[i] = f2bf(((const float*)fcwv)[i]);
    else               FCW[i] = ((const unsigned short*)fcwv)[i];
  }
  if (tid < INDIM) {
    if constexpr (F32) FCB[tid] = ((const float*)fcbv)[tid];
    else               FCB[tid] = bf2f(((const unsigned short*)fcbv)[tid]);
  }

  auto ld1 = [&](const void* p, int i) -> float {
    if constexpr (F32) return ((const float*)p)[i];
    else               return bf2f(((const unsigned short*)p)[i]);
  };
  auto ld8 = [&](const void* W, int off) -> bf16x8 {
    union { unsigned short us[8]; bf16x8 v; } t;
    if constexpr (F32) {
      const float* p = (const float*)W + off;
#pragma unroll
      for (int j = 0; j < 8; ++j) t.us[j] = f2bf(p[j]);
    } else {
      t.v = *(const bf16x8*)((const unsigned short*)W + off);
    }
    return t.v;
  };

  // ---- per-role weight fragments (bias folded into MFMA C operand) ----
  bf16x8 WA[12]; f32x4 bvA[4];   // role 0
  bf16x8 WB[16]; f32x4 bvB[4];   // role 1
  if (role == 0) {
#pragma unroll
    for (int gt = 0; gt < 4; ++gt) {
      const int col = 64 * gt + u;
      WA[gt * 3 + 0] = ld8(Whh0v, col * HDIM + 8 * q);
      WA[gt * 3 + 1] = ld8(Whh0v, col * HDIM + 32 + 8 * q);
      union { unsigned short us[8]; bf16x8 v; } t2;
#pragma unroll
      for (int j = 0; j < 8; ++j) t2.us[j] = 0;
      if (q == 0) {
#pragma unroll
        for (int j = 0; j < INDIM; ++j) t2.us[j] = f2bf(ld1(Wih0v, col * INDIM + j));
      }
      WA[gt * 3 + 2] = t2.v;
      const float b = ld1(bih0v, col) + ld1(bhh0v, col);
      bvA[gt] = (f32x4){b, b, b, b};
    }
  } else if (role == 1) {
#pragma unroll
    for (int gt = 0; gt < 4; ++gt) {
      const int col = 64 * gt + u;
      WB[gt * 4 + 0] = ld8(Wih1v, col * HDIM + 8 * q);
      WB[gt * 4 + 1] = ld8(Wih1v, col * HDIM + 32 + 8 * q);
      WB[gt * 4 + 2] = ld8(Whh1v, col * HDIM + 8 * q);
      WB[gt * 4 + 3] = ld8(Whh1v, col * HDIM + 32 + 8 * q);
      const float b = ld1(bih1v, col) + ld1(bhh1v, col);
      bvB[gt] = (f32x4){b, b, b, b};
    }
  }

  // ---- x chunk staging (all threads, uniform) ----
  auto load_chunk = [&](int t0c) {
    if constexpr (F32) {
      const char* xb = (const char*)xv;
      for (int c = tid; c < NROWS * (CHNK * INDIM / 4); c += 1024) {  // 48 float4/row
        const int row = c / 48;
        const int off = c - row * 48;
        const float4 v = *(const float4*)(xb + (size_t)(rbase + row) * (T_SEQ * INDIM * 4)
                                             + (size_t)t0c * (INDIM * 4) + (size_t)off * 16);
        us4 o;
        o.x = f2bf(v.x); o.y = f2bf(v.y); o.z = f2bf(v.z); o.w = f2bf(v.w);
        *(us4*)((char*)XB + (size_t)c * 8) = o;
      }
    } else {
      const char* xb = (const char*)xv;
      for (int c = tid; c < NROWS * (CHNK * INDIM / 8); c += 1024) {  // 24 16B-chunks/row
        const int row = c / 24;
        const int off = c - row * 24;
        const int4 v = *(const int4*)(xb + (size_t)(rbase + row) * (T_SEQ * INDIM * 2)
                                         + (size_t)t0c * (INDIM * 2) + (size_t)off * 16);
        *(int4*)((char*)XB + (size_t)c * 16) = v;
      }
    }
  };

  load_chunk(0);
  __syncthreads();

  // x-writer lanes live in act-L0 waves (tid 512..607)
  const int tid2   = tid - 512;
  const bool xw    = (tid2 >= 0 && tid2 < NROWS * INDIM);
  const int xrow2  = xw ? (tid2 / INDIM) : 0;
  const int xk2    = xw ? (tid2 - xrow2 * INDIM) : 0;
  const int xWrOff = xrow2 * S0 + HDIM + xk2;
  const int xbBase = xrow2 * (CHNK * INDIM) + xk2;

  if (xw) A0[0][xWrOff] = XB[xbBase];   // x_0
  __syncthreads();

  const int aOff   = n * S0 + 8 * q;                 // MFMA A-frag offset
  const int gwBase = (16 * wv + n) * GSTR + 4 * q;   // MFMA G-write float idx
  const int a      = wv;                             // act roles: row group 4a..4a+3
  const int grBase = lane * GSTR + 4 * a;            // act G-read float idx
  const int hBase  = 4 * a * S0 + lane;              // act h-write elem idx

  float cc[4] = {0.f, 0.f, 0.f, 0.f};   // c0 (role 2) / c1 (role 3)

  // ---- encoder: iter i: A-MFMA gates for h0(i); B-MFMA gates for h1(i-1);
  //      act-L0 turns G0 -> h0(i); act-L1 turns G1 -> h1(i-1). ----
  int t0v = 0;
  for (int i = 0; i <= T_SEQ; ++i) {
    if (((i + 1) & (CHNK - 1)) == 0 && (i + 1) < T_SEQ) {
      load_chunk(i + 1);
      __syncthreads();
      t0v = i + 1;
    }
    const int cur = i & 1;
    // phase M
    if (role == 0) {
      if (i < T_SEQ) {
        const unsigned short* A0c = &A0[cur][0];
        const bf16x8 f0 = *(const bf16x8*)(A0c + aOff);
        const bf16x8 f1 = *(const bf16x8*)(A0c + aOff + 32);
        const bf16x8 f2 = *(const bf16x8*)(A0c + aOff + 64);
#pragma unroll
        for (int gt = 0; gt < 4; ++gt) {
          f32x4 g = MFMA16(f0, WA[gt * 3 + 0], bvA[gt]);
          g       = MFMA16(f1, WA[gt * 3 + 1], g);
          g       = MFMA16(f2, WA[gt * 3 + 2], g);
          *(f32x4*)&G0[gwBase + gt * (HDIM * GSTR)] = g;
        }
      }
    } else if (role == 1) {
      if (i >= 1) {
        const unsigned short* A0c = &A0[cur][0];
        const unsigned short* A1c = &A1[cur][0];
        const bf16x8 h0a = *(const bf16x8*)(A0c + aOff);
        const bf16x8 h0b = *(const bf16x8*)(A0c + aOff + 32);
        const bf16x8 r0  = *(const bf16x8*)(A1c + aOff);
        const bf16x8 r1  = *(const bf16x8*)(A1c + aOff + 32);
#pragma unroll
        for (int gt = 0; gt < 4; ++gt) {
          f32x4 g = MFMA16(h0a, WB[gt * 4 + 0], bvB[gt]);
          g       = MFMA16(h0b, WB[gt * 4 + 1], g);
          g       = MFMA16(r0,  WB[gt * 4 + 2], g);
          g       = MFMA16(r1,  WB[gt * 4 + 3], g);
          *(f32x4*)&G1[gwBase + gt * (HDIM * GSTR)] = g;
        }
      }
    }
    __syncthreads();
    // phase act
    if (role == 2) {
      if (i < T_SEQ) {
        const f32x4 gi = *(const f32x4*)&G0[grBase];
        const f32x4 gf = *(const f32x4*)&G0[grBase + 1 * (HDIM * GSTR)];
        const f32x4 gg = *(const f32x4*)&G0[grBase + 2 * (HDIM * GSTR)];
        const f32x4 go = *(const f32x4*)&G0[grBase + 3 * (HDIM * GSTR)];
        unsigned short* dst = &A0[cur ^ 1][0];
#pragma unroll
        for (int r = 0; r < 4; ++r) {
          const float is = sigf(gi[r]);
          const float fs = sigf(gf[r]);
          const float gv = tanh_f(gg[r]);
          const float os = sigf(go[r]);
          cc[r] = fs * cc[r] + is * gv;
          dst[hBase + r * S0] = f2bf(os * tanh_f(cc[r]));
        }
        const int srct = (i + 1 < T_SEQ) ? (i + 1) : (T_SEQ - 1);
        if (xw) dst[xWrOff] = XB[xbBase + (srct - t0v) * INDIM];
      }
    } else if (role == 3) {
      if (i >= 1) {
        const f32x4 gi = *(const f32x4*)&G1[grBase];
        const f32x4 gf = *(const f32x4*)&G1[grBase + 1 * (HDIM * GSTR)];
        const f32x4 gg = *(const f32x4*)&G1[grBase + 2 * (HDIM * GSTR)];
        const f32x4 go = *(const f32x4*)&G1[grBase + 3 * (HDIM * GSTR)];
        unsigned short* dst = &A1[cur ^ 1][0];
#pragma unroll
        for (int r = 0; r < 4; ++r) {
          const float is = sigf(gi[r]);
          const float fs = sigf(gf[r]);
          const float gv = tanh_f(gg[r]);
          const float os = sigf(go[r]);
          cc[r] = fs * cc[r] + is * gv;
          dst[hBase + r * S0] = f2bf(os * tanh_f(cc[r]));
        }
      }
    }
    __syncthreads();
  }
  // state: A0[0] = [h0(1023), x(1023)]; A1[1] = h1(1023); c in act-lane regs.

  // ---- decoder: 10 serial steps, in place; 5 phases/step ----
  unsigned short* H0 = &A0[0][0];
  unsigned short* H1 = &A1[1][0];
  for (int d = 0; d < NPRED; ++d) {
    // D1: L0 gates from [h0, x]
    if (role == 0) {
      const bf16x8 f0 = *(const bf16x8*)(H0 + aOff);
      const bf16x8 f1 = *(const bf16x8*)(H0 + aOff + 32);
      const bf16x8 f2 = *(const bf16x8*)(H0 + aOff + 64);
#pragma unroll
      for (int gt = 0; gt < 4; ++gt) {
        f32x4 g = MFMA16(f0, WA[gt * 3 + 0], bvA[gt]);
        g       = MFMA16(f1, WA[gt * 3 + 1], g);
        g       = MFMA16(f2, WA[gt * 3 + 2], g);
        *(f32x4*)&G0[gwBase + gt * (HDIM * GSTR)] = g;
      }
    }
    __syncthreads();
    // D2: act-L0 -> h0 in place
    if (role == 2) {
      const f32x4 gi = *(const f32x4*)&G0[grBase];
      const f32x4 gf = *(const f32x4*)&G0[grBase + 1 * (HDIM * GSTR)];
      const f32x4 gg = *(const f32x4*)&G0[grBase + 2 * (HDIM * GSTR)];
      const f32x4 go = *(const f32x4*)&G0[grBase + 3 * (HDIM * GSTR)];
#pragma unroll
      for (int r = 0; r < 4; ++r) {
        const float is = sigf(gi[r]);
        const float fs = sigf(gf[r]);
        const float gv = tanh_f(gg[r]);
        const float os = sigf(go[r]);
        cc[r] = fs * cc[r] + is * gv;
        H0[hBase + r * S0] = f2bf(os * tanh_f(cc[r]));
      }
    }
    __syncthreads();
    // D3: L1 gates from fresh h0 + prev h1
    if (role == 1) {
      const bf16x8 h0a = *(const bf16x8*)(H0 + aOff);
      const bf16x8 h0b = *(const bf16x8*)(H0 + aOff + 32);
      const bf16x8 r0  = *(const bf16x8*)(H1 + aOff);
      const bf16x8 r1  = *(const bf16x8*)(H1 + aOff + 32);
#pragma unroll
      for (int gt = 0; gt < 4; ++gt) {
        f32x4 g = MFMA16(h0a, WB[gt * 4 + 0], bvB[gt]);
        g       = MFMA16(h0b, WB[gt * 4 + 1], g);
        g       = MFMA16(r0,  WB[gt * 4 + 2], g);
        g       = MFMA16(r1,  WB[gt * 4 + 3], g);
        *(f32x4*)&G1[gwBase + gt * (HDIM * GSTR)] = g;
      }
    }
    __syncthreads();
    // D4: act-L1 -> h1 in place
    if (role == 3) {
      const f32x4 gi = *(const f32x4*)&G1[grBase];
      const f32x4 gf = *(const f32x4*)&G1[grBase + 1 * (HDIM * GSTR)];
      const f32x4 gg = *(const f32x4*)&G1[grBase + 2 * (HDIM * GSTR)];
      const f32x4 go = *(const f32x4*)&G1[grBase + 3 * (HDIM * GSTR)];
#pragma unroll
      for (int r = 0; r < 4; ++r) {
        const float is = sigf(gi[r]);
        const float fs = sigf(gf[r]);
        const float gv = tanh_f(gg[r]);
        const float os = sigf(go[r]);
        cc[r] = fs * cc[r] + is * gv;
        H1[hBase + r * S0] = f2bf(os * tanh_f(cc[r]));
      }
    }
    __syncthreads();
    // D5: FC head + feedback (lanes 512..607, inside act-L0 waves)
    if (xw) {
      const unsigned short* h1row = H1 + xrow2 * S0;
      const int4* hp = (const int4*)h1row;
      const int4* wp = (const int4*)(&FCW[xk2 * HDIM]);
      float s = FCB[xk2];
#pragma unroll
      for (int i8 = 0; i8 < 8; ++i8) {
        const int4 hv = hp[i8];
        const int4 wv2 = wp[i8];
        const unsigned int hu[4] = {(unsigned)hv.x, (unsigned)hv.y, (unsigned)hv.z, (unsigned)hv.w};
        const unsigned int wu[4] = {(unsigned)wv2.x, (unsigned)wv2.y, (unsigned)wv2.z, (unsigned)wv2.w};
#pragma unroll
        for (int k2 = 0; k2 < 4; ++k2) {
          union { unsigned int uu; float ff; } hl, hh2, wl, wh;
          hl.uu = hu[k2] << 16; hh2.uu = hu[k2] & 0xFFFF0000u;
          wl.uu = wu[k2] << 16; wh.uu  = wu[k2] & 0xFFFF0000u;
          s += hl.ff * wl.ff + hh2.ff * wh.ff;
        }
      }
      const unsigned short pb = f2bf(s);
      const size_t idx = (size_t)(rbase + xrow2) * (NPRED * INDIM) + (size_t)d * INDIM + xk2;
      if constexpr (F32) ((float*)outv)[idx] = s;
      else               ((unsigned short*)outv)[idx] = pb;
      H0[xWrOff] = pb;   // next decoder input
    }
    __syncthreads();
  }
}

extern "C" void kernel_launch(void* const* d_in, const int* in_sizes, int n_in,
                              void* d_out, int out_size, void* d_ws, size_t ws_size,
                              hipStream_t stream) {
  (void)in_sizes; (void)n_in; (void)d_ws; (void)ws_size; (void)out_size;
  const void* x    = d_in[0];
  const void* Wih0 = d_in[1];
  const void* Whh0 = d_in[2];
  const void* bih0 = d_in[3];
  const void* bhh0 = d_in[4];
  const void* Wih1 = d_in[5];
  const void* Whh1 = d_in[6];
  const void* bih1 = d_in[7];
  const void* bhh1 = d_in[8];
  const void* fcw  = d_in[9];
  const void* fcb  = d_in[10];
  // Exactly one instance does the work (device-side dtype sniff).
  lstm2_split<true><<<dim3(4096 / NROWS), dim3(1024), 0, stream>>>(
      x, Wih0, Whh0, bih0, bhh0, Wih1, Whh1, bih1, bhh1, fcw, fcb, d_out);
  lstm2_split<false><<<dim3(4096 / NROWS), dim3(1024), 0, stream>>>(
      x, Wih0, Whh0, bih0, bhh0, Wih1, Whh1, bih1, bhh1, fcw, fcb, d_out);
}

// Round 10
// 1208.897 us; speedup vs baseline: 2.6838x; 2.6838x over previous
//
#include <hip/hip_runtime.h>

#define T_SEQ   1024
#define INDIM   6
#define HDIM    64
#define NPRED   10
#define CHNK    128
#define S0      104      // LDS row stride (elements) for A-operand buffers
#define NROWS   16       // batch rows per workgroup (grid 256 = 1 block/CU)

typedef __bf16         bf16x8 __attribute__((ext_vector_type(8)));
typedef float          f32x4  __attribute__((ext_vector_type(4)));
typedef unsigned short us4    __attribute__((ext_vector_type(4)));

#define MFMA16(a, b, c) __builtin_amdgcn_mfma_f32_16x16x32_bf16((a), (b), (c), 0, 0, 0)

static __device__ __forceinline__ float bf2f(unsigned short b) {
  union { unsigned int u; float f; } v; v.u = ((unsigned int)b) << 16; return v.f;
}
static __device__ __forceinline__ unsigned short f2bf(float f) {
  union { float f; unsigned int u; } v; v.f = f;
  unsigned int r = v.u + 0x7FFFu + ((v.u >> 16) & 1u);
  return (unsigned short)(r >> 16);
}
static __device__ __forceinline__ float sigf(float x) {
  return __builtin_amdgcn_rcpf(1.0f + __builtin_amdgcn_exp2f(x * -1.442695040888963f));
}
static __device__ __forceinline__ float tanh_f(float x) {
  return 2.0f * __builtin_amdgcn_rcpf(1.0f + __builtin_amdgcn_exp2f(x * -2.885390081777927f)) - 1.0f;
}

// Anti-phase layer-pipelined 2-layer LSTM. Waves 0-3 = L0 engine (A), waves
// 4-7 = L1 engine (B, lagging 2 steps). Per encoder iter, two phases:
//   ph1: A-MFMA gates(i)      || B-act gates(i-2) -> h1(i-2)
//   ph2: A-act  -> h0(i)      || B-MFMA gates(i-1) from h0(i-1), h1(i-2)
// so every phase pairs a MFMA-bound wave with a VALU-bound wave per SIMD.
// Gates persist in registers across the barrier. Engine loops duplicated
// under a wave-uniform branch with identical barrier counts (r8-verified).
template <bool F32>
__global__ __launch_bounds__(512, 2)
void lstm2_stag(const void* __restrict__ xv,
                const void* __restrict__ Wih0v,
                const void* __restrict__ Whh0v,
                const void* __restrict__ bih0v,
                const void* __restrict__ bhh0v,
                const void* __restrict__ Wih1v,
                const void* __restrict__ Whh1v,
                const void* __restrict__ bih1v,
                const void* __restrict__ bhh1v,
                const void* __restrict__ fcwv,
                const void* __restrict__ fcbv,
                void* __restrict__ outv)
{
  // ---- dtype sniff (uniform) ----
  {
    const unsigned short* w0u = (const unsigned short*)Wih0v;
    int votes = 0;
#pragma unroll
    for (int i = 0; i < 16; ++i) {
      const unsigned e = (w0u[2 * i] >> 7) & 0xFF;
      votes += (e >= 0x80 || e <= 0x40) ? 1 : 0;
    }
    if ((votes >= 4) != F32) return;
  }

  // A0[b]: [row][k]: k 0..63 = h0, 64..69 = x, 70..95 zero pad. A1[b]: h1.
  __shared__ __align__(16) unsigned short A0[2][NROWS * S0];
  __shared__ __align__(16) unsigned short A1[2][NROWS * S0];
  __shared__ __align__(16) unsigned short XB[NROWS * CHNK * INDIM];
  __shared__ __align__(16) unsigned short FCW[INDIM * HDIM];
  __shared__ float FCB[INDIM];

  const int tid   = threadIdx.x;
  const int lane  = tid & 63;
  const int wave  = tid >> 6;
  const bool isA  = (wave < 4);
  const int  wv4  = wave & 3;
  const int  q    = lane >> 4;
  const int  n    = lane & 15;
  const int  u    = 16 * wv4 + n;
  const int rbase = blockIdx.x * NROWS;

  {
    unsigned short* p0 = &A0[0][0];
    unsigned short* p1 = &A1[0][0];
    for (int i = tid; i < 2 * NROWS * S0; i += 512) { p0[i] = 0; p1[i] = 0; }
  }
  for (int i = tid; i < INDIM * HDIM; i += 512) {
    if constexpr (F32) FCW[i] = f2bf(((const float*)fcwv)[i]);
    else               FCW[i] = ((const unsigned short*)fcwv)[i];
  }
  if (tid < INDIM) {
    if constexpr (F32) FCB[tid] = ((const float*)fcbv)[tid];
    else               FCB[tid] = bf2f(((const unsigned short*)fcbv)[tid]);
  }

  auto ld1 = [&](const void* p, int i) -> float {
    if constexpr (F32) return ((const float*)p)[i];
    else               return bf2f(((const unsigned short*)p)[i]);
  };
  auto ld8 = [&](const void* W, int off) -> bf16x8 {
    union { unsigned short us[8]; bf16x8 v; } t;
    if constexpr (F32) {
      const float* p = (const float*)W + off;
#pragma unroll
      for (int j = 0; j < 8; ++j) t.us[j] = f2bf(p[j]);
    } else {
      t.v = *(const bf16x8*)((const unsigned short*)W + off);
    }
    return t.v;
  };

  auto load_chunk = [&](int t0c) {
    if constexpr (F32) {
      const char* xb = (const char*)xv;
      for (int c = tid; c < NROWS * 192; c += 512) {
        const int row = c / 192;
        const int off = c - row * 192;
        const float4 v = *(const float4*)(xb + (size_t)(rbase + row) * (T_SEQ * INDIM * 4)
                                             + (size_t)t0c * (INDIM * 4) + (size_t)off * 16);
        us4 o;
        o.x = f2bf(v.x); o.y = f2bf(v.y); o.z = f2bf(v.z); o.w = f2bf(v.w);
        *(us4*)((char*)XB + (size_t)c * 8) = o;
      }
    } else {
      const char* xb = (const char*)xv;
      for (int c = tid; c < NROWS * 96; c += 512) {
        const int row = c / 96;
        const int off = c - row * 96;
        const int4 v = *(const int4*)(xb + (size_t)(rbase + row) * (T_SEQ * INDIM * 2)
                                         + (size_t)t0c * (INDIM * 2) + (size_t)off * 16);
        *(int4*)((char*)XB + (size_t)c * 16) = v;
      }
    }
  };

  load_chunk(0);
  __syncthreads();

  const int xrow   = tid / INDIM;                 // valid for tid < 96 (A waves)
  const int xk     = tid - xrow * INDIM;
  const int xWrOff = xrow * S0 + HDIM + xk;
  const int xbBase = xrow * (CHNK * INDIM) + xk;

  if (tid < 96) A0[0][xWrOff] = XB[xbBase];       // x_0 into buffer holding h0(-1)
  __syncthreads();

  const int aOff = n * S0 + 8 * q;   // A-frag: row m = n, k = 8q..8q+7 (+32*s)
  const int hOff = (4 * q) * S0 + u; // C-layout write: rows 4q+r, col u

  float cc[4] = {0.f, 0.f, 0.f, 0.f};

  unsigned short* H0 = &A0[1][0];    // after encoder: h0(1023) ++ x(1023)
  unsigned short* H1 = &A1[1][0];    // after encoder: h1(1023)

  if (isA) {
    // ================= layer-0 engine =================
    bf16x8 WA[12]; f32x4 bvA[4];
#pragma unroll
    for (int gt = 0; gt < 4; ++gt) {
      const int col = 64 * gt + u;
      WA[gt * 3 + 0] = ld8(Whh0v, col * HDIM + 8 * q);
      WA[gt * 3 + 1] = ld8(Whh0v, col * HDIM + 32 + 8 * q);
      union { unsigned short us[8]; bf16x8 v; } t2;
#pragma unroll
      for (int j = 0; j < 8; ++j) t2.us[j] = 0;
      if (q == 0) {
#pragma unroll
        for (int j = 0; j < INDIM; ++j) t2.us[j] = f2bf(ld1(Wih0v, col * INDIM + j));
      }
      WA[gt * 3 + 2] = t2.v;
      const float b = ld1(bih0v, col) + ld1(bhh0v, col);
      bvA[gt] = (f32x4){b, b, b, b};
    }

    f32x4 g0 = {}, g1 = {}, g2 = {}, g3 = {};
    int t0v = 0;
    for (int i = 0; i <= T_SEQ + 1; ++i) {
      if (((i + 1) & (CHNK - 1)) == 0 && (i + 1) < T_SEQ) {
        load_chunk(i + 1);
        __syncthreads();
        t0v = i + 1;
      }
      // ph1: A-MFMA gates(i) from A0[(i-1)&1] = A0[(i+1)&1]
      if (i < T_SEQ) {
        const unsigned short* Ac = &A0[(i + 1) & 1][0];
        const bf16x8 f0 = *(const bf16x8*)(Ac + aOff);
        const bf16x8 f1 = *(const bf16x8*)(Ac + aOff + 32);
        const bf16x8 f2 = *(const bf16x8*)(Ac + aOff + 64);
        g0 = MFMA16(f0, WA[0], bvA[0]); g0 = MFMA16(f1, WA[1],  g0); g0 = MFMA16(f2, WA[2],  g0);
        g1 = MFMA16(f0, WA[3], bvA[1]); g1 = MFMA16(f1, WA[4],  g1); g1 = MFMA16(f2, WA[5],  g1);
        g2 = MFMA16(f0, WA[6], bvA[2]); g2 = MFMA16(f1, WA[7],  g2); g2 = MFMA16(f2, WA[8],  g2);
        g3 = MFMA16(f0, WA[9], bvA[3]); g3 = MFMA16(f1, WA[10], g3); g3 = MFMA16(f2, WA[11], g3);
      }
      __syncthreads();
      // ph2: A-act -> h0(i) into A0[i&1] (+ x(i+1))
      if (i < T_SEQ) {
        unsigned short* An = &A0[i & 1][0];
#pragma unroll
        for (int r = 0; r < 4; ++r) {
          const float is = sigf(g0[r]);
          const float fs = sigf(g1[r]);
          const float gv = tanh_f(g2[r]);
          const float os = sigf(g3[r]);
          cc[r] = fs * cc[r] + is * gv;
          An[hOff + r * S0] = f2bf(os * tanh_f(cc[r]));
        }
        const int srct = (i + 1 < T_SEQ) ? (i + 1) : (T_SEQ - 1);
        if (tid < 96) An[xWrOff] = XB[xbBase + (srct - t0v) * INDIM];
      }
      __syncthreads();
    }
    // decoder, engine A (4 barriers/step, mirrored in B)
    for (int d = 0; d < NPRED; ++d) {
      const bf16x8 fa0 = *(const bf16x8*)(H0 + aOff);
      const bf16x8 fa1 = *(const bf16x8*)(H0 + aOff + 32);
      const bf16x8 fa2 = *(const bf16x8*)(H0 + aOff + 64);
      __syncthreads();                      // ph1
      {
        f32x4 d0 = MFMA16(fa0, WA[0], bvA[0]); d0 = MFMA16(fa1, WA[1],  d0); d0 = MFMA16(fa2, WA[2],  d0);
        f32x4 d1 = MFMA16(fa0, WA[3], bvA[1]); d1 = MFMA16(fa1, WA[4],  d1); d1 = MFMA16(fa2, WA[5],  d1);
        f32x4 d2 = MFMA16(fa0, WA[6], bvA[2]); d2 = MFMA16(fa1, WA[7],  d2); d2 = MFMA16(fa2, WA[8],  d2);
        f32x4 d3 = MFMA16(fa0, WA[9], bvA[3]); d3 = MFMA16(fa1, WA[10], d3); d3 = MFMA16(fa2, WA[11], d3);
#pragma unroll
        for (int r = 0; r < 4; ++r) {
          const float is = sigf(d0[r]);
          const float fs = sigf(d1[r]);
          const float gv = tanh_f(d2[r]);
          const float os = sigf(d3[r]);
          cc[r] = fs * cc[r] + is * gv;
          H0[hOff + r * S0] = f2bf(os * tanh_f(cc[r]));
        }
      }
      __syncthreads();                      // ph2
      __syncthreads();                      // ph3 (B computes h1)
      if (tid < 96) {                       // ph4: FC head + feedback
        const unsigned short* h1row = H1 + xrow * S0;
        const int4* hp = (const int4*)h1row;
        const int4* wp = (const int4*)(&FCW[xk * HDIM]);
        float s = FCB[xk];
#pragma unroll
        for (int i8 = 0; i8 < 8; ++i8) {
          const int4 hv = hp[i8];
          const int4 wv2 = wp[i8];
          const unsigned int hu[4] = {(unsigned)hv.x, (unsigned)hv.y, (unsigned)hv.z, (unsigned)hv.w};
          const unsigned int wu[4] = {(unsigned)wv2.x, (unsigned)wv2.y, (unsigned)wv2.z, (unsigned)wv2.w};
#pragma unroll
          for (int k2 = 0; k2 < 4; ++k2) {
            union { unsigned int uu; float ff; } hl, hh2, wl, wh;
            hl.uu = hu[k2] << 16; hh2.uu = hu[k2] & 0xFFFF0000u;
            wl.uu = wu[k2] << 16; wh.uu  = wu[k2] & 0xFFFF0000u;
            s += hl.ff * wl.ff + hh2.ff * wh.ff;
          }
        }
        const unsigned short pb = f2bf(s);
        const size_t idx = (size_t)(rbase + xrow) * (NPRED * INDIM) + (size_t)d * INDIM + xk;
        if constexpr (F32) ((float*)outv)[idx] = s;
        else               ((unsigned short*)outv)[idx] = pb;
        H0[xWrOff] = pb;
      }
      __syncthreads();                      // ph4 end
    }
  } else {
    // ================= layer-1 engine (lag 2) =================
    bf16x8 WB[16]; f32x4 bvB[4];
#pragma unroll
    for (int gt = 0; gt < 4; ++gt) {
      const int col = 64 * gt + u;
      WB[gt * 4 + 0] = ld8(Wih1v, col * HDIM + 8 * q);
      WB[gt * 4 + 1] = ld8(Wih1v, col * HDIM + 32 + 8 * q);
      WB[gt * 4 + 2] = ld8(Whh1v, col * HDIM + 8 * q);
      WB[gt * 4 + 3] = ld8(Whh1v, col * HDIM + 32 + 8 * q);
      const float b = ld1(bih1v, col) + ld1(bhh1v, col);
      bvB[gt] = (f32x4){b, b, b, b};
    }

    f32x4 g0 = {}, g1 = {}, g2 = {}, g3 = {};  // gates(i-1), produced ph2, used next ph1
    for (int i = 0; i <= T_SEQ + 1; ++i) {
      if (((i + 1) & (CHNK - 1)) == 0 && (i + 1) < T_SEQ) {
        load_chunk(i + 1);
        __syncthreads();
      }
      // ph1: B-act gates(i-2) -> h1(i-2) into A1[i&1]  ((i-2)&1 == i&1)
      if (i >= 2) {
        unsigned short* An = &A1[i & 1][0];
#pragma unroll
        for (int r = 0; r < 4; ++r) {
          const float is = sigf(g0[r]);
          const float fs = sigf(g1[r]);
          const float gv = tanh_f(g2[r]);
          const float os = sigf(g3[r]);
          cc[r] = fs * cc[r] + is * gv;
          An[hOff + r * S0] = f2bf(os * tanh_f(cc[r]));
        }
      }
      __syncthreads();
      // ph2: B-MFMA gates(i-1) from h0(i-1)=A0[(i+1)&1], h1(i-2)=A1[i&1]
      if (i >= 1 && i <= T_SEQ) {
        const unsigned short* A0c = &A0[(i + 1) & 1][0];
        const unsigned short* A1c = &A1[i & 1][0];
        const bf16x8 h0a = *(const bf16x8*)(A0c + aOff);
        const bf16x8 h0b = *(const bf16x8*)(A0c + aOff + 32);
        const bf16x8 r0  = *(const bf16x8*)(A1c + aOff);
        const bf16x8 r1  = *(const bf16x8*)(A1c + aOff + 32);
        g0 = MFMA16(h0a, WB[0],  bvB[0]); g0 = MFMA16(h0b, WB[1],  g0); g0 = MFMA16(r0, WB[2],  g0); g0 = MFMA16(r1, WB[3],  g0);
        g1 = MFMA16(h0a, WB[4],  bvB[1]); g1 = MFMA16(h0b, WB[5],  g1); g1 = MFMA16(r0, WB[6],  g1); g1 = MFMA16(r1, WB[7],  g1);
        g2 = MFMA16(h0a, WB[8],  bvB[2]); g2 = MFMA16(h0b, WB[9],  g2); g2 = MFMA16(r0, WB[10], g2); g2 = MFMA16(r1, WB[11], g2);
        g3 = MFMA16(h0a, WB[12], bvB[3]); g3 = MFMA16(h0b, WB[13], g3); g3 = MFMA16(r0, WB[14], g3); g3 = MFMA16(r1, WB[15], g3);
      }
      __syncthreads();
    }
    // decoder, engine B (4 barriers/step, mirrored with A)
    for (int d = 0; d < NPRED; ++d) {
      const bf16x8 fr0 = *(const bf16x8*)(H1 + aOff);
      const bf16x8 fr1 = *(const bf16x8*)(H1 + aOff + 32);
      __syncthreads();                      // ph1
      __syncthreads();                      // ph2 (A computes h0)
      {
        const bf16x8 h0a = *(const bf16x8*)(H0 + aOff);
        const bf16x8 h0b = *(const bf16x8*)(H0 + aOff + 32);
        f32x4 d0 = MFMA16(h0a, WB[0],  bvB[0]); d0 = MFMA16(h0b, WB[1],  d0); d0 = MFMA16(fr0, WB[2],  d0); d0 = MFMA16(fr1, WB[3],  d0);
        f32x4 d1 = MFMA16(h0a, WB[4],  bvB[1]); d1 = MFMA16(h0b, WB[5],  d1); d1 = MFMA16(fr0, WB[6],  d1); d1 = MFMA16(fr1, WB[7],  d1);
        f32x4 d2 = MFMA16(h0a, WB[8],  bvB[2]); d2 = MFMA16(h0b, WB[9],  d2); d2 = MFMA16(fr0, WB[10], d2); d2 = MFMA16(fr1, WB[11], d2);
        f32x4 d3 = MFMA16(h0a, WB[12], bvB[3]); d3 = MFMA16(h0b, WB[13], d3); d3 = MFMA16(fr0, WB[14], d3); d3 = MFMA16(fr1, WB[15], d3);
#pragma unroll
        for (int r = 0; r < 4; ++r) {
          const float is = sigf(d0[r]);
          const float fs = sigf(d1[r]);
          const float gv = tanh_f(d2[r]);
          const float os = sigf(d3[r]);
          cc[r] = fs * cc[r] + is * gv;
          H1[hOff + r * S0] = f2bf(os * tanh_f(cc[r]));
        }
      }
      __syncthreads();                      // ph3
      __syncthreads();                      // ph4 (A does FC head)
    }
  }
}

extern "C" void kernel_launch(void* const* d_in, const int* in_sizes, int n_in,
                              void* d_out, int out_size, void* d_ws, size_t ws_size,
                              hipStream_t stream) {
  (void)in_sizes; (void)n_in; (void)d_ws; (void)ws_size; (void)out_size;
  const void* x    = d_in[0];
  const void* Wih0 = d_in[1];
  const void* Whh0 = d_in[2];
  const void* bih0 = d_in[3];
  const void* bhh0 = d_in[4];
  const void* Wih1 = d_in[5];
  const void* Whh1 = d_in[6];
  const void* bih1 = d_in[7];
  const void* bhh1 = d_in[8];
  const void* fcw  = d_in[9];
  const void* fcb  = d_in[10];
  // Exactly one instance does the work (device-side dtype sniff).
  lstm2_stag<true><<<dim3(4096 / NROWS), dim3(512), 0, stream>>>(
      x, Wih0, Whh0, bih0, bhh0, Wih1, Whh1, bih1, bhh1, fcw, fcb, d_out);
  lstm2_stag<false><<<dim3(4096 / NROWS), dim3(512), 0, stream>>>(
      x, Wih0, Whh0, bih0, bhh0, Wih1, Whh1, bih1, bhh1, fcw, fcb, d_out);
}

// Round 11
// 957.469 us; speedup vs baseline: 3.3886x; 1.2626x over previous
//
#include <hip/hip_runtime.h>

#define T_SEQ   1024
#define INDIM   6
#define HDIM    64
#define NPRED   10
#define CHNK    128
#define S0      104      // LDS row stride (elements) for A-operand buffers
#define NROWS   16       // batch rows per workgroup (grid 256 = 1 block/CU)

typedef __bf16         bf16x8 __attribute__((ext_vector_type(8)));
typedef float          f32x4  __attribute__((ext_vector_type(4)));
typedef unsigned short us4    __attribute__((ext_vector_type(4)));

#define MFMA16(a, b, c) __builtin_amdgcn_mfma_f32_16x16x32_bf16((a), (b), (c), 0, 0, 0)

static __device__ __forceinline__ float bf2f(unsigned short b) {
  union { unsigned int u; float f; } v; v.u = ((unsigned int)b) << 16; return v.f;
}
static __device__ __forceinline__ unsigned short f2bf(float f) {
  union { float f; unsigned int u; } v; v.f = f;
  unsigned int r = v.u + 0x7FFFu + ((v.u >> 16) & 1u);
  return (unsigned short)(r >> 16);
}

// r6 skeleton (layer-pipelined, ONE barrier/encoder step) + diet:
//  - duplicated engine loops (each wave holds only its own weights)
//  - bias folded into MFMA C operand
//  - combined-rcp cell update (exact algebra, overflow-safe), 8 trans/cell
template <bool F32>
__global__ __launch_bounds__(512, 2)
void lstm2_pipe(const void* __restrict__ xv,
                const void* __restrict__ Wih0v,
                const void* __restrict__ Whh0v,
                const void* __restrict__ bih0v,
                const void* __restrict__ bhh0v,
                const void* __restrict__ Wih1v,
                const void* __restrict__ Whh1v,
                const void* __restrict__ bih1v,
                const void* __restrict__ bhh1v,
                const void* __restrict__ fcwv,
                const void* __restrict__ fcbv,
                void* __restrict__ outv)
{
  // ---- dtype sniff (uniform) ----
  {
    const unsigned short* w0u = (const unsigned short*)Wih0v;
    int votes = 0;
#pragma unroll
    for (int i = 0; i < 16; ++i) {
      const unsigned e = (w0u[2 * i] >> 7) & 0xFF;
      votes += (e >= 0x80 || e <= 0x40) ? 1 : 0;
    }
    if ((votes >= 4) != F32) return;
  }

  // A0[b]: [row][k]: k 0..63 = h0, 64..69 = x, 70..95 zero pad. A1[b]: h1.
  __shared__ __align__(16) unsigned short A0[2][NROWS * S0];
  __shared__ __align__(16) unsigned short A1[2][NROWS * S0];
  __shared__ __align__(16) unsigned short XB[NROWS * CHNK * INDIM];
  __shared__ __align__(16) unsigned short FCW[INDIM * HDIM];
  __shared__ float FCB[INDIM];

  const int tid   = threadIdx.x;
  const int lane  = tid & 63;
  const int wave  = tid >> 6;
  const bool isA  = (wave < 4);
  const int  wv4  = wave & 3;
  const int  q    = lane >> 4;
  const int  n    = lane & 15;
  const int  u    = 16 * wv4 + n;
  const int rbase = blockIdx.x * NROWS;

  {
    unsigned short* p0 = &A0[0][0];
    unsigned short* p1 = &A1[0][0];
    for (int i = tid; i < 2 * NROWS * S0; i += 512) { p0[i] = 0; p1[i] = 0; }
  }
  for (int i = tid; i < INDIM * HDIM; i += 512) {
    if constexpr (F32) FCW[i] = f2bf(((const float*)fcwv)[i]);
    else               FCW[i] = ((const unsigned short*)fcwv)[i];
  }
  if (tid < INDIM) {
    if constexpr (F32) FCB[tid] = ((const float*)fcbv)[tid];
    else               FCB[tid] = bf2f(((const unsigned short*)fcbv)[tid]);
  }

  auto ld1 = [&](const void* p, int i) -> float {
    if constexpr (F32) return ((const float*)p)[i];
    else               return bf2f(((const unsigned short*)p)[i]);
  };
  auto ld8 = [&](const void* W, int off) -> bf16x8 {
    union { unsigned short us[8]; bf16x8 v; } t;
    if constexpr (F32) {
      const float* p = (const float*)W + off;
#pragma unroll
      for (int j = 0; j < 8; ++j) t.us[j] = f2bf(p[j]);
    } else {
      t.v = *(const bf16x8*)((const unsigned short*)W + off);
    }
    return t.v;
  };

  auto load_chunk = [&](int t0c) {
    if constexpr (F32) {
      const char* xb = (const char*)xv;
      for (int c = tid; c < NROWS * 192; c += 512) {
        const int row = c / 192;
        const int off = c - row * 192;
        const float4 v = *(const float4*)(xb + (size_t)(rbase + row) * (T_SEQ * INDIM * 4)
                                             + (size_t)t0c * (INDIM * 4) + (size_t)off * 16);
        us4 o;
        o.x = f2bf(v.x); o.y = f2bf(v.y); o.z = f2bf(v.z); o.w = f2bf(v.w);
        *(us4*)((char*)XB + (size_t)c * 8) = o;
      }
    } else {
      const char* xb = (const char*)xv;
      for (int c = tid; c < NROWS * 96; c += 512) {
        const int row = c / 96;
        const int off = c - row * 96;
        const int4 v = *(const int4*)(xb + (size_t)(rbase + row) * (T_SEQ * INDIM * 2)
                                         + (size_t)t0c * (INDIM * 2) + (size_t)off * 16);
        *(int4*)((char*)XB + (size_t)c * 16) = v;
      }
    }
  };

  load_chunk(0);
  __syncthreads();

  const int xrow   = tid / INDIM;                 // valid for tid < 96 (A waves)
  const int xk     = tid - xrow * INDIM;
  const int xWrOff = xrow * S0 + HDIM + xk;
  const int xbBase = xrow * (CHNK * INDIM) + xk;

  if (tid < 96) A0[0][xWrOff] = XB[xbBase];       // x_0
  __syncthreads();

  const int aOff = n * S0 + 8 * q;   // A-frag: row m = n, k = 8q..8q+7 (+32*s)
  const int hOff = (4 * q) * S0 + u; // C-layout write: rows 4q+r, col u

  float cc[4] = {0.f, 0.f, 0.f, 0.f};

  // Combined-rcp LSTM cell update. gI/gF/gG/gO = raw gates (bias included).
  //   A=e^-f, B=e^-i, G=e^-2g, M1=(1+B)(1+G)
  //   c' = [c*M1 + (1-G)(1+A)] / ((1+A)*M1)      (exact algebra, 1 rcp)
  //   h  = rcp(1+e^-o) * (2*rcp(1+e^-2c') - 1)   (saturating-safe for any c)
  auto act4 = [&](const f32x4 gI, const f32x4 gF, const f32x4 gG, const f32x4 gO,
                  unsigned short* dst) {
#pragma unroll
    for (int r = 0; r < 4; ++r) {
      const float Ae = __builtin_amdgcn_exp2f(gF[r] * -1.442695040888963f);
      const float Be = __builtin_amdgcn_exp2f(gI[r] * -1.442695040888963f);
      const float Ge = __builtin_amdgcn_exp2f(gG[r] * -2.885390081777927f);
      const float M1 = (1.0f + Be) * (1.0f + Ge);
      const float nm = cc[r] * M1 + (1.0f - Ge) * (1.0f + Ae);
      cc[r] = nm * __builtin_amdgcn_rcpf((1.0f + Ae) * M1);
      const float Oe = __builtin_amdgcn_exp2f(gO[r] * -1.442695040888963f);
      const float tc = 2.0f * __builtin_amdgcn_rcpf(
                         1.0f + __builtin_amdgcn_exp2f(cc[r] * -2.885390081777927f)) - 1.0f;
      dst[hOff + r * S0] = f2bf(__builtin_amdgcn_rcpf(1.0f + Oe) * tc);
    }
  };

  unsigned short* H0 = &A0[0][0];    // after encoder: h0(1023) ++ x(1023)
  unsigned short* H1 = &A1[1][0];    // after encoder: h1(1023)

  if (isA) {
    // ================= layer-0 engine =================
    bf16x8 WA[12]; f32x4 bvA[4];
#pragma unroll
    for (int gt = 0; gt < 4; ++gt) {
      const int col = 64 * gt + u;
      WA[gt * 3 + 0] = ld8(Whh0v, col * HDIM + 8 * q);
      WA[gt * 3 + 1] = ld8(Whh0v, col * HDIM + 32 + 8 * q);
      union { unsigned short us[8]; bf16x8 v; } t2;
#pragma unroll
      for (int j = 0; j < 8; ++j) t2.us[j] = 0;
      if (q == 0) {
#pragma unroll
        for (int j = 0; j < INDIM; ++j) t2.us[j] = f2bf(ld1(Wih0v, col * INDIM + j));
      }
      WA[gt * 3 + 2] = t2.v;
      const float b = ld1(bih0v, col) + ld1(bhh0v, col);
      bvA[gt] = (f32x4){b, b, b, b};
    }

    int t0v = 0;
    for (int i = 0; i <= T_SEQ; ++i) {
      if (((i + 1) & (CHNK - 1)) == 0 && (i + 1) < T_SEQ) {
        load_chunk(i + 1);
        __syncthreads();
        t0v = i + 1;
      }
      const int cur = i & 1;
      if (i < T_SEQ) {
        const unsigned short* A0c = &A0[cur][0];
        unsigned short*       A0n = &A0[cur ^ 1][0];
        const bf16x8 f0 = *(const bf16x8*)(A0c + aOff);
        const bf16x8 f1 = *(const bf16x8*)(A0c + aOff + 32);
        const bf16x8 f2 = *(const bf16x8*)(A0c + aOff + 64);
        f32x4 g0 = MFMA16(f0, WA[0], bvA[0]); g0 = MFMA16(f1, WA[1],  g0); g0 = MFMA16(f2, WA[2],  g0);
        f32x4 g1 = MFMA16(f0, WA[3], bvA[1]); g1 = MFMA16(f1, WA[4],  g1); g1 = MFMA16(f2, WA[5],  g1);
        f32x4 g2 = MFMA16(f0, WA[6], bvA[2]); g2 = MFMA16(f1, WA[7],  g2); g2 = MFMA16(f2, WA[8],  g2);
        f32x4 g3 = MFMA16(f0, WA[9], bvA[3]); g3 = MFMA16(f1, WA[10], g3); g3 = MFMA16(f2, WA[11], g3);
        act4(g0, g1, g2, g3, A0n);
        const int srct = (i + 1 < T_SEQ) ? (i + 1) : (T_SEQ - 1);
        if (tid < 96) A0n[xWrOff] = XB[xbBase + (srct - t0v) * INDIM];
      }
      __syncthreads();
    }
    // decoder, engine A (4 barriers/step, mirrored in B)
    for (int d = 0; d < NPRED; ++d) {
      const bf16x8 fa0 = *(const bf16x8*)(H0 + aOff);
      const bf16x8 fa1 = *(const bf16x8*)(H0 + aOff + 32);
      const bf16x8 fa2 = *(const bf16x8*)(H0 + aOff + 64);
      __syncthreads();                      // ph1
      {
        f32x4 g0 = MFMA16(fa0, WA[0], bvA[0]); g0 = MFMA16(fa1, WA[1],  g0); g0 = MFMA16(fa2, WA[2],  g0);
        f32x4 g1 = MFMA16(fa0, WA[3], bvA[1]); g1 = MFMA16(fa1, WA[4],  g1); g1 = MFMA16(fa2, WA[5],  g1);
        f32x4 g2 = MFMA16(fa0, WA[6], bvA[2]); g2 = MFMA16(fa1, WA[7],  g2); g2 = MFMA16(fa2, WA[8],  g2);
        f32x4 g3 = MFMA16(fa0, WA[9], bvA[3]); g3 = MFMA16(fa1, WA[10], g3); g3 = MFMA16(fa2, WA[11], g3);
        act4(g0, g1, g2, g3, H0);
      }
      __syncthreads();                      // ph2
      __syncthreads();                      // ph3 (B computes h1)
      if (tid < 96) {                       // ph4: FC head + feedback
        const unsigned short* h1row = H1 + xrow * S0;
        const int4* hp = (const int4*)h1row;
        const int4* wp = (const int4*)(&FCW[xk * HDIM]);
        float s = FCB[xk];
#pragma unroll
        for (int i8 = 0; i8 < 8; ++i8) {
          const int4 hv = hp[i8];
          const int4 wv2 = wp[i8];
          const unsigned int hu[4] = {(unsigned)hv.x, (unsigned)hv.y, (unsigned)hv.z, (unsigned)hv.w};
          const unsigned int wu[4] = {(unsigned)wv2.x, (unsigned)wv2.y, (unsigned)wv2.z, (unsigned)wv2.w};
#pragma unroll
          for (int k2 = 0; k2 < 4; ++k2) {
            union { unsigned int uu; float ff; } hl, hh2, wl, wh;
            hl.uu = hu[k2] << 16; hh2.uu = hu[k2] & 0xFFFF0000u;
            wl.uu = wu[k2] << 16; wh.uu  = wu[k2] & 0xFFFF0000u;
            s += hl.ff * wl.ff + hh2.ff * wh.ff;
          }
        }
        const unsigned short pb = f2bf(s);
        const size_t idx = (size_t)(rbase + xrow) * (NPRED * INDIM) + (size_t)d * INDIM + xk;
        if constexpr (F32) ((float*)outv)[idx] = s;
        else               ((unsigned short*)outv)[idx] = pb;
        H0[xWrOff] = pb;
      }
      __syncthreads();                      // ph4 end
    }
  } else {
    // ================= layer-1 engine (lag 1) =================
    bf16x8 WB[16]; f32x4 bvB[4];
#pragma unroll
    for (int gt = 0; gt < 4; ++gt) {
      const int col = 64 * gt + u;
      WB[gt * 4 + 0] = ld8(Wih1v, col * HDIM + 8 * q);
      WB[gt * 4 + 1] = ld8(Wih1v, col * HDIM + 32 + 8 * q);
      WB[gt * 4 + 2] = ld8(Whh1v, col * HDIM + 8 * q);
      WB[gt * 4 + 3] = ld8(Whh1v, col * HDIM + 32 + 8 * q);
      const float b = ld1(bih1v, col) + ld1(bhh1v, col);
      bvB[gt] = (f32x4){b, b, b, b};
    }

    for (int i = 0; i <= T_SEQ; ++i) {
      if (((i + 1) & (CHNK - 1)) == 0 && (i + 1) < T_SEQ) {
        load_chunk(i + 1);
        __syncthreads();
      }
      const int cur = i & 1;
      if (i >= 1) {
        const unsigned short* A0c = &A0[cur][0];
        const unsigned short* A1c = &A1[cur][0];
        unsigned short*       A1n = &A1[cur ^ 1][0];
        const bf16x8 h0a = *(const bf16x8*)(A0c + aOff);
        const bf16x8 h0b = *(const bf16x8*)(A0c + aOff + 32);
        const bf16x8 r0  = *(const bf16x8*)(A1c + aOff);
        const bf16x8 r1  = *(const bf16x8*)(A1c + aOff + 32);
        f32x4 g0 = MFMA16(h0a, WB[0],  bvB[0]); g0 = MFMA16(h0b, WB[1],  g0); g0 = MFMA16(r0, WB[2],  g0); g0 = MFMA16(r1, WB[3],  g0);
        f32x4 g1 = MFMA16(h0a, WB[4],  bvB[1]); g1 = MFMA16(h0b, WB[5],  g1); g1 = MFMA16(r0, WB[6],  g1); g1 = MFMA16(r1, WB[7],  g1);
        f32x4 g2 = MFMA16(h0a, WB[8],  bvB[2]); g2 = MFMA16(h0b, WB[9],  g2); g2 = MFMA16(r0, WB[10], g2); g2 = MFMA16(r1, WB[11], g2);
        f32x4 g3 = MFMA16(h0a, WB[12], bvB[3]); g3 = MFMA16(h0b, WB[13], g3); g3 = MFMA16(r0, WB[14], g3); g3 = MFMA16(r1, WB[15], g3);
        act4(g0, g1, g2, g3, A1n);
      }
      __syncthreads();
    }
    // decoder, engine B (4 barriers/step, mirrored with A)
    for (int d = 0; d < NPRED; ++d) {
      const bf16x8 fr0 = *(const bf16x8*)(H1 + aOff);
      const bf16x8 fr1 = *(const bf16x8*)(H1 + aOff + 32);
      __syncthreads();                      // ph1
      __syncthreads();                      // ph2 (A computes h0)
      {
        const bf16x8 h0a = *(const bf16x8*)(H0 + aOff);
        const bf16x8 h0b = *(const bf16x8*)(H0 + aOff + 32);
        f32x4 g0 = MFMA16(h0a, WB[0],  bvB[0]); g0 = MFMA16(h0b, WB[1],  g0); g0 = MFMA16(fr0, WB[2],  g0); g0 = MFMA16(fr1, WB[3],  g0);
        f32x4 g1 = MFMA16(h0a, WB[4],  bvB[1]); g1 = MFMA16(h0b, WB[5],  g1); g1 = MFMA16(fr0, WB[6],  g1); g1 = MFMA16(fr1, WB[7],  g1);
        f32x4 g2 = MFMA16(h0a, WB[8],  bvB[2]); g2 = MFMA16(h0b, WB[9],  g2); g2 = MFMA16(fr0, WB[10], g2); g2 = MFMA16(fr1, WB[11], g2);
        f32x4 g3 = MFMA16(h0a, WB[12], bvB[3]); g3 = MFMA16(h0b, WB[13], g3); g3 = MFMA16(fr0, WB[14], g3); g3 = MFMA16(fr1, WB[15], g3);
        act4(g0, g1, g2, g3, H1);
      }
      __syncthreads();                      // ph3
      __syncthreads();                      // ph4 (A does FC head)
    }
  }
}

extern "C" void kernel_launch(void* const* d_in, const int* in_sizes, int n_in,
                              void* d_out, int out_size, void* d_ws, size_t ws_size,
                              hipStream_t stream) {
  (void)in_sizes; (void)n_in; (void)d_ws; (void)ws_size; (void)out_size;
  const void* x    = d_in[0];
  const void* Wih0 = d_in[1];
  const void* Whh0 = d_in[2];
  const void* bih0 = d_in[3];
  const void* bhh0 = d_in[4];
  const void* Wih1 = d_in[5];
  const void* Whh1 = d_in[6];
  const void* bih1 = d_in[7];
  const void* bhh1 = d_in[8];
  const void* fcw  = d_in[9];
  const void* fcb  = d_in[10];
  // Exactly one instance does the work (device-side dtype sniff).
  lstm2_pipe<true><<<dim3(4096 / NROWS), dim3(512), 0, stream>>>(
      x, Wih0, Whh0, bih0, bhh0, Wih1, Whh1, bih1, bhh1, fcw, fcb, d_out);
  lstm2_pipe<false><<<dim3(4096 / NROWS), dim3(512), 0, stream>>>(
      x, Wih0, Whh0, bih0, bhh0, Wih1, Whh1, bih1, bhh1, fcw, fcb, d_out);
}